// Round 11
// baseline (193.890 us; speedup 1.0000x reference)
//
#include <hip/hip_runtime.h>
#include <stdint.h>

// Problem constants
#define Bsz 4096
#define Tn  64      // scan length (char_seq[:, :-1])
#define T1n 65
#define Hn  64
#define Pn  50
#define Vn  32

typedef __attribute__((ext_vector_type(8))) short short8;
typedef __attribute__((ext_vector_type(4))) float floatx4;

__device__ __forceinline__ float bf2f(unsigned short u) {
  union { unsigned int i; float f; } x; x.i = ((unsigned int)u) << 16; return x.f;
}
__device__ __forceinline__ unsigned short f2bf(float f) {
  union { float f; unsigned int i; } x; x.f = f;
  return (unsigned short)((x.i + 0x7FFFu + ((x.i >> 16) & 1u)) >> 16);
}
__device__ __forceinline__ float fast_sigmoid(float x) {
  return __builtin_amdgcn_rcpf(1.f + __expf(-x));
}
__device__ __forceinline__ float fast_tanh(float x) {
  return 1.f - 2.f * __builtin_amdgcn_rcpf(1.f + __expf(2.f * x));
}

// B-operand fragment for mfma_f32_16x16x32_bf16 from row-major (K x ncols) fp32 weights.
__device__ __forceinline__ short8 load_bfrag(const float* __restrict__ W, int ncols, int col, int kbase) {
  short8 f;
#pragma unroll
  for (int j = 0; j < 8; ++j) f[j] = (short)f2bf(W[(long)(kbase + j) * ncols + col]);
  return f;
}

// Producer/consumer fused GRU (R9 structure + dedicated softmax waves).
// 256 blocks x 512 threads (8 waves). Block owns 16 batch rows.
// Waves 0-3 (scan): r-gate (interval A) + c-gate/h-update (interval B).
// Waves 4-7: z-gate in A (16 cols each). In B: waves 4-5 project h_{t-1}
// (fp32 logits staged in LDS); waves 6-7 run softmax/NLL/store of page t-2
// (wave 6: rows 0-7, wave 7: rows 8-15). Uniform 2-barrier cadence; global
// stores issue continuously from waves whose drain never gates the barrier.
__launch_bounds__(512)
__global__ void gru_kernel(const float* __restrict__ phon,
                           const int* __restrict__ cs,
                           const float* __restrict__ emb,
                           const float* __restrict__ Wrx, const float* __restrict__ brx,
                           const float* __restrict__ Wrh, const float* __restrict__ brh,
                           const float* __restrict__ Wzx, const float* __restrict__ bzx,
                           const float* __restrict__ Wzh, const float* __restrict__ bzh,
                           const float* __restrict__ Whx, const float* __restrict__ bhx,
                           const float* __restrict__ Whh, const float* __restrict__ bhh,
                           const float* __restrict__ Wpj, const float* __restrict__ bpj_g,
                           float* __restrict__ ws,
                           float* __restrict__ outp) {
  __shared__ unsigned short tbl_s[3 * 32 * 66];             // bf16 [g][v][66]
  __shared__ __align__(16) unsigned short hist_s[8 * 1152]; // bf16 h[t&7][m][72]
  __shared__ __align__(16) unsigned short rh_s[1152];       // bf16 r*h [m][72]
  __shared__ float z_s[16 * 68];                            // f32 z [m][68]
  __shared__ float logit_s[8 * 16 * 33];                    // f32 [page&7][m][33]
  __shared__ unsigned int code4_s[(T1n + 1) * 4];           // packed codes [t][q]
  __shared__ int det_s[1];
  __shared__ float red_s[16];

  const int tid = threadIdx.x;
  const int b0 = blockIdx.x * 16;
  const int W8 = tid >> 6, lane = tid & 63, q = lane >> 4, c16 = lane & 15;
  const bool isScan = (W8 < 4);
  const int w = isScan ? W8 : (W8 - 4);
  const int jcol = w * 16 + c16;
  const floatx4 zf = {0.f, 0.f, 0.f, 0.f};

  // --- int32-vs-int64 detection for char_seq ---
  if (tid == 0) det_s[0] = 0;
  __syncthreads();
  if (tid < 128 && cs[2 * tid + 1] != 0) atomicOr(&det_s[0], 1);
  __syncthreads();
  const bool is64 = (det_s[0] == 0);

  // --- staging ---
  for (int i = tid; i < 1152; i += 512) hist_s[7 * 1152 + i] = 0;   // h0 slot
  for (int i = tid; i < T1n * 4; i += 512) {
    int t = i >> 2, qq = i & 3;
    unsigned int pk = 0;
#pragma unroll
    for (int r = 0; r < 4; ++r) {
      long idx = (long)(b0 + qq * 4 + r) * T1n + t;
      int c = is64 ? cs[2 * idx] : cs[idx];
      pk |= ((unsigned int)(c & 255)) << (8 * r);
    }
    code4_s[i] = pk;
  }

  // --- TBL: tbl_s[g][v][j] = bf16( emb[v] @ W_gx[:64] + b_gx[j] + b_gh[j] ) ---
  for (int g = 0; g < 3; ++g) {
    const float* Wg = (g == 0) ? Wrx : (g == 1) ? Wzx : Whx;
    const float* bx = (g == 0) ? brx : (g == 1) ? bzx : bhx;
    const float* bh = (g == 0) ? brh : (g == 1) ? bzh : bhh;
    float acc[4] = {0.f, 0.f, 0.f, 0.f};
    float bias = bx[lane] + bh[lane];
    for (int d = 0; d < Hn; ++d) {
      float wv = Wg[(long)d * Hn + lane];
#pragma unroll
      for (int k = 0; k < 4; ++k)
        acc[k] += emb[(long)(W8 + 8 * k) * Hn + d] * wv;
    }
#pragma unroll
    for (int k = 0; k < 4; ++k)
      tbl_s[g * 2112 + (W8 + 8 * k) * 66 + lane] = f2bf(acc[k] + bias);
  }

  // --- PH per-lane: scan waves need r,h gates; aux waves need z gate ---
  float ph_a[4] = {0.f, 0.f, 0.f, 0.f};  // scan: r-gate | aux: z-gate
  float ph_h[4] = {0.f, 0.f, 0.f, 0.f};  // scan only
  {
    const float* Wa = isScan ? Wrx : Wzx;
    for (int p = 0; p < Pn; ++p) {
      float wa = Wa[(long)(Hn + p) * Hn + jcol];
      float wh = isScan ? Whx[(long)(Hn + p) * Hn + jcol] : 0.f;
#pragma unroll
      for (int r = 0; r < 4; ++r) {
        float xv = phon[(long)(b0 + q * 4 + r) * Pn + p];
        ph_a[r] += xv * wa;
        ph_h[r] += xv * wh;
      }
    }
  }

  // --- B-fragments (register-resident, t-invariant) ---
  short8 Ba0, Ba1;   // scan: W_rh | aux: W_zh
  short8 Bh0, Bh1;   // scan: W_hh
  short8 Bp0, Bp1;   // waves 4,5: W_proj (vocab tile W8-4)
  float bpj = 0.f;
  {
    const float* Wa = isScan ? Wrh : Wzh;
    Ba0 = load_bfrag(Wa, Hn, jcol, q * 8);
    Ba1 = load_bfrag(Wa, Hn, jcol, 32 + q * 8);
    Bh0 = Ba0; Bh1 = Ba1; Bp0 = Ba0; Bp1 = Ba1;
    if (isScan) {
      Bh0 = load_bfrag(Whh, Hn, jcol, q * 8);
      Bh1 = load_bfrag(Whh, Hn, jcol, 32 + q * 8);
    } else if (W8 < 6) {
      int vt = W8 - 4;
      Bp0 = load_bfrag(Wpj, Vn, vt * 16 + c16, q * 8);
      Bp1 = load_bfrag(Wpj, Vn, vt * 16 + c16, 32 + q * 8);
      bpj = bpj_g[vt * 16 + c16];
    }
  }

  float h[4] = {0.f, 0.f, 0.f, 0.f};
  float nll = 0.f, cnt = 0.f;

  __syncthreads();   // prologue done

  for (int t = 0; t < Tn; ++t) {
    const unsigned int pk = code4_s[t * 4 + q];
    // ===== interval A =====
    {
      const unsigned short* hp = &hist_s[((t + 7) & 7) * 1152];
      short8 a0 = *(const short8*)&hp[c16 * 72 + q * 8];
      short8 a1 = *(const short8*)&hp[c16 * 72 + 32 + q * 8];
      floatx4 acc = __builtin_amdgcn_mfma_f32_16x16x32_bf16(a0, Ba0, zf, 0, 0, 0);
      acc = __builtin_amdgcn_mfma_f32_16x16x32_bf16(a1, Ba1, acc, 0, 0, 0);
      if (isScan) {       // r-gate -> rh_s
#pragma unroll
        for (int r = 0; r < 4; ++r) {
          int cr = (pk >> (8 * r)) & 255;
          float xr = bf2f(tbl_s[0 * 2112 + cr * 66 + jcol]) + ph_a[r] + acc[r];
          rh_s[(q * 4 + r) * 72 + jcol] = f2bf(fast_sigmoid(xr) * h[r]);
        }
      } else {            // z-gate -> z_s (f32)
#pragma unroll
        for (int r = 0; r < 4; ++r) {
          int cr = (pk >> (8 * r)) & 255;
          float xz = bf2f(tbl_s[1 * 2112 + cr * 66 + jcol]) + ph_a[r] + acc[r];
          z_s[(q * 4 + r) * 68 + jcol] = fast_sigmoid(xz);
        }
      }
    }
    __syncthreads();  // A

    // ===== interval B =====
    if (isScan) {       // c-gate + h-update -> hist_s[t&7]
      short8 p0 = *(const short8*)&rh_s[c16 * 72 + q * 8];
      short8 p1 = *(const short8*)&rh_s[c16 * 72 + 32 + q * 8];
      floatx4 acc = __builtin_amdgcn_mfma_f32_16x16x32_bf16(p0, Bh0, zf, 0, 0, 0);
      acc = __builtin_amdgcn_mfma_f32_16x16x32_bf16(p1, Bh1, acc, 0, 0, 0);
      unsigned short* hw = &hist_s[(t & 7) * 1152];
#pragma unroll
      for (int r = 0; r < 4; ++r) {
        int cr = (pk >> (8 * r)) & 255;
        float xh = bf2f(tbl_s[2 * 2112 + cr * 66 + jcol]) + ph_h[r] + acc[r];
        float c = fast_tanh(xh);
        float zr = z_s[(q * 4 + r) * 68 + jcol];
        float hn = (1.f - zr) * h[r] + zr * c;
        h[r] = hn;
        hw[(q * 4 + r) * 72 + jcol] = f2bf(hn);
      }
    } else if (W8 < 6) {   // waves 4-5: project h_{t-1} -> logit stage
      if (t > 0) {
        const unsigned short* hp = &hist_s[((t + 7) & 7) * 1152];
        short8 a0 = *(const short8*)&hp[c16 * 72 + q * 8];
        short8 a1 = *(const short8*)&hp[c16 * 72 + 32 + q * 8];
        floatx4 l = __builtin_amdgcn_mfma_f32_16x16x32_bf16(a0, Bp0, zf, 0, 0, 0);
        l = __builtin_amdgcn_mfma_f32_16x16x32_bf16(a1, Bp1, l, 0, 0, 0);
        float* pg = &logit_s[((t - 1) & 7) * 528];
        int vt = W8 - 4;
#pragma unroll
        for (int r = 0; r < 4; ++r)
          pg[(q * 4 + r) * 33 + vt * 16 + c16] = l[r] + bpj;
      }
    } else {               // waves 6-7: softmax/NLL/store of page t-2
      int p = t - 2;
      if (p >= 0) {
        const float* pg = &logit_s[(p & 7) * 528];
        int v = lane & 31, hf = lane >> 5;
        int mbase = (W8 == 6) ? 0 : 8;
#pragma unroll
        for (int i = 0; i < 4; ++i) {
          int m = mbase + i * 2 + hf;
          float lg = pg[m * 33 + v];
          float s = __expf(lg);
#pragma unroll
          for (int off = 16; off >= 1; off >>= 1) s += __shfl_xor(s, off);
          float lse = __logf(s);     // |logits| <= ~8, safe without max-sub
          outp[(((long)(b0 + m)) * Tn + p) * Vn + v] = lg;
          unsigned int pk1 = code4_s[(p + 1) * 4 + (m >> 2)];
          int targ = (pk1 >> (8 * (m & 3))) & 255;
          if (targ != 0 && v == targ) { nll += lse - lg; cnt += 1.f; }
        }
      }
    }
    __syncthreads();  // B
  }

  // ===== epilogue: stage page 63, then softmax pages 62, 63 =====
  if (W8 >= 4 && W8 < 6) {
    const unsigned short* hp = &hist_s[7 * 1152];   // h_63
    short8 a0 = *(const short8*)&hp[c16 * 72 + q * 8];
    short8 a1 = *(const short8*)&hp[c16 * 72 + 32 + q * 8];
    floatx4 l = __builtin_amdgcn_mfma_f32_16x16x32_bf16(a0, Bp0, zf, 0, 0, 0);
    l = __builtin_amdgcn_mfma_f32_16x16x32_bf16(a1, Bp1, l, 0, 0, 0);
    int vt = W8 - 4;
#pragma unroll
    for (int r = 0; r < 4; ++r)
      logit_s[7 * 528 + (q * 4 + r) * 33 + vt * 16 + c16] = l[r] + bpj;
  }
  __syncthreads();
  if (W8 >= 6) {
    int p = (W8 == 6) ? 62 : 63;
    const float* pg = &logit_s[(p & 7) * 528];
    int v = lane & 31, hf = lane >> 5;
#pragma unroll
    for (int i = 0; i < 8; ++i) {
      int m = i * 2 + hf;
      float lg = pg[m * 33 + v];
      float s = __expf(lg);
#pragma unroll
      for (int off = 16; off >= 1; off >>= 1) s += __shfl_xor(s, off);
      float lse = __logf(s);
      outp[(((long)(b0 + m)) * Tn + p) * Vn + v] = lg;
      unsigned int pk1 = code4_s[(p + 1) * 4 + (m >> 2)];
      int targ = (pk1 >> (8 * (m & 3))) & 255;
      if (targ != 0 && v == targ) { nll += lse - lg; cnt += 1.f; }
    }
  }

  // ===== reduction -> per-block ws slot =====
#pragma unroll
  for (int off = 32; off >= 1; off >>= 1) {
    nll += __shfl_xor(nll, off);
    cnt += __shfl_xor(cnt, off);
  }
  if (lane == 0) { red_s[W8] = nll; red_s[8 + W8] = cnt; }
  __syncthreads();
  if (tid == 0) {
    float n = 0.f, c = 0.f;
#pragma unroll
    for (int i = 0; i < 8; ++i) { n += red_s[i]; c += red_s[8 + i]; }
    ws[2 * blockIdx.x] = n;
    ws[2 * blockIdx.x + 1] = c;
  }
}

__global__ void loss_kernel(const float* __restrict__ ws, float* __restrict__ outp) {
  int lane = threadIdx.x;  // 64 threads
  float n = 0.f, c = 0.f;
  for (int i = lane; i < Bsz / 16; i += 64) { n += ws[2 * i]; c += ws[2 * i + 1]; }
#pragma unroll
  for (int off = 32; off >= 1; off >>= 1) {
    n += __shfl_xor(n, off);
    c += __shfl_xor(c, off);
  }
  if (lane == 0) outp[(size_t)Bsz * Tn * Vn] = n / fmaxf(c, 1.f);
}

extern "C" void kernel_launch(void* const* d_in, const int* in_sizes, int n_in,
                              void* d_out, int out_size, void* d_ws, size_t ws_size,
                              hipStream_t stream) {
  const float* phon = (const float*)d_in[0];
  const int*   cs   = (const int*)d_in[1];
  const float* emb  = (const float*)d_in[2];
  const float* Wrx  = (const float*)d_in[3];
  const float* brx  = (const float*)d_in[4];
  const float* Wrh  = (const float*)d_in[5];
  const float* brh  = (const float*)d_in[6];
  const float* Wzx  = (const float*)d_in[7];
  const float* bzx  = (const float*)d_in[8];
  const float* Wzh  = (const float*)d_in[9];
  const float* bzh  = (const float*)d_in[10];
  const float* Whx  = (const float*)d_in[11];
  const float* bhx  = (const float*)d_in[12];
  const float* Whh  = (const float*)d_in[13];
  const float* bhh  = (const float*)d_in[14];
  const float* Wpj  = (const float*)d_in[15];
  const float* bpj  = (const float*)d_in[16];
  float* ws = (float*)d_ws;

  hipLaunchKernelGGL(gru_kernel, dim3(Bsz / 16), dim3(512), 0, stream,
                     phon, cs, emb, Wrx, brx, Wrh, brh, Wzx, bzx, Wzh, bzh,
                     Whx, bhx, Whh, bhh, Wpj, bpj, ws, (float*)d_out);
  hipLaunchKernelGGL(loss_kernel, dim3(1), dim3(64), 0, stream, ws, (float*)d_out);
}

// Round 12
// 175.613 us; speedup vs baseline: 1.1041x; 1.1041x over previous
//
#include <hip/hip_runtime.h>
#include <stdint.h>

// Problem constants
#define Bsz 4096
#define Tn  64      // scan length (char_seq[:, :-1])
#define T1n 65
#define Hn  64
#define Pn  50
#define Vn  32

typedef __attribute__((ext_vector_type(8))) short short8;
typedef __attribute__((ext_vector_type(4))) float floatx4;

__device__ __forceinline__ float bf2f(unsigned short u) {
  union { unsigned int i; float f; } x; x.i = ((unsigned int)u) << 16; return x.f;
}
__device__ __forceinline__ unsigned short f2bf(float f) {
  union { float f; unsigned int i; } x; x.f = f;
  return (unsigned short)((x.i + 0x7FFFu + ((x.i >> 16) & 1u)) >> 16);
}
__device__ __forceinline__ float fast_sigmoid(float x) {
  return __builtin_amdgcn_rcpf(1.f + __expf(-x));
}
__device__ __forceinline__ float fast_tanh(float x) {
  return 1.f - 2.f * __builtin_amdgcn_rcpf(1.f + __expf(2.f * x));
}

// B-operand fragment for mfma_f32_16x16x32_bf16 from row-major (K x ncols) fp32 weights.
__device__ __forceinline__ short8 load_bfrag(const float* __restrict__ W, int ncols, int col, int kbase) {
  short8 f;
#pragma unroll
  for (int j = 0; j < 8; ++j) f[j] = (short)f2bf(W[(long)(kbase + j) * ncols + col]);
  return f;
}

// Producer/consumer fused GRU (R9 structure; z exchange via column-major b128,
// c-gate TBL reads hoisted into interval A).
// 256 blocks x 512 threads (8 waves). Block owns 16 batch rows.
// Waves 0-3 (scan): r-gate (A) + c-gate/h-update (B) for cols [16w,16w+16).
// Waves 4-7 (aux): z-gate in A (b128 -> z_cm); waves 4-5 project h_{t-1} in B.
// Tail: every 8 steps, all 8 waves each softmax one page (parallel across pages).
__launch_bounds__(512)
__global__ void gru_kernel(const float* __restrict__ phon,
                           const int* __restrict__ cs,
                           const float* __restrict__ emb,
                           const float* __restrict__ Wrx, const float* __restrict__ brx,
                           const float* __restrict__ Wrh, const float* __restrict__ brh,
                           const float* __restrict__ Wzx, const float* __restrict__ bzx,
                           const float* __restrict__ Wzh, const float* __restrict__ bzh,
                           const float* __restrict__ Whx, const float* __restrict__ bhx,
                           const float* __restrict__ Whh, const float* __restrict__ bhh,
                           const float* __restrict__ Wpj, const float* __restrict__ bpj_g,
                           float* __restrict__ ws,
                           float* __restrict__ outp) {
  __shared__ unsigned short tbl_s[3 * 32 * 66];             // bf16 [g][v][66]
  __shared__ __align__(16) unsigned short hist_s[8 * 1152]; // bf16 h[t&7][m][72]
  __shared__ __align__(16) unsigned short rh_s[1152];       // bf16 r*h [m][72]
  __shared__ __align__(16) float z_cm[64 * 20];             // f32 z [col][m], stride 20
  __shared__ float logit_s[8 * 16 * 33];                    // f32 [page&7][m][33]
  __shared__ unsigned int code4_s[(T1n + 1) * 4];           // packed codes [t][q]
  __shared__ int det_s[1];
  __shared__ float red_s[16];

  const int tid = threadIdx.x;
  const int b0 = blockIdx.x * 16;
  const int W8 = tid >> 6, lane = tid & 63, q = lane >> 4, c16 = lane & 15;
  const bool isScan = (W8 < 4);
  const int w = isScan ? W8 : (W8 - 4);
  const int jcol = w * 16 + c16;
  const floatx4 zf = {0.f, 0.f, 0.f, 0.f};

  // --- int32-vs-int64 detection for char_seq ---
  if (tid == 0) det_s[0] = 0;
  __syncthreads();
  if (tid < 128 && cs[2 * tid + 1] != 0) atomicOr(&det_s[0], 1);
  __syncthreads();
  const bool is64 = (det_s[0] == 0);

  // --- staging ---
  for (int i = tid; i < 1152; i += 512) hist_s[7 * 1152 + i] = 0;   // h0 slot
  for (int i = tid; i < T1n * 4; i += 512) {
    int t = i >> 2, qq = i & 3;
    unsigned int pk = 0;
#pragma unroll
    for (int r = 0; r < 4; ++r) {
      long idx = (long)(b0 + qq * 4 + r) * T1n + t;
      int c = is64 ? cs[2 * idx] : cs[idx];
      pk |= ((unsigned int)(c & 255)) << (8 * r);
    }
    code4_s[i] = pk;
  }

  // --- TBL: tbl_s[g][v][j] = bf16( emb[v] @ W_gx[:64] + b_gx[j] + b_gh[j] ) ---
  for (int g = 0; g < 3; ++g) {
    const float* Wg = (g == 0) ? Wrx : (g == 1) ? Wzx : Whx;
    const float* bx = (g == 0) ? brx : (g == 1) ? bzx : bhx;
    const float* bh = (g == 0) ? brh : (g == 1) ? bzh : bhh;
    float acc[4] = {0.f, 0.f, 0.f, 0.f};
    float bias = bx[lane] + bh[lane];
    for (int d = 0; d < Hn; ++d) {
      float wv = Wg[(long)d * Hn + lane];
#pragma unroll
      for (int k = 0; k < 4; ++k)
        acc[k] += emb[(long)(W8 + 8 * k) * Hn + d] * wv;
    }
#pragma unroll
    for (int k = 0; k < 4; ++k)
      tbl_s[g * 2112 + (W8 + 8 * k) * 66 + lane] = f2bf(acc[k] + bias);
  }

  // --- PH per-lane: scan waves need r,h gates; aux waves need z gate ---
  float ph_a[4] = {0.f, 0.f, 0.f, 0.f};  // scan: r-gate | aux: z-gate
  float ph_h[4] = {0.f, 0.f, 0.f, 0.f};  // scan only
  {
    const float* Wa = isScan ? Wrx : Wzx;
    for (int p = 0; p < Pn; ++p) {
      float wa = Wa[(long)(Hn + p) * Hn + jcol];
      float wh = isScan ? Whx[(long)(Hn + p) * Hn + jcol] : 0.f;
#pragma unroll
      for (int r = 0; r < 4; ++r) {
        float xv = phon[(long)(b0 + q * 4 + r) * Pn + p];
        ph_a[r] += xv * wa;
        ph_h[r] += xv * wh;
      }
    }
  }

  // --- B-fragments (register-resident, t-invariant) ---
  short8 Ba0, Ba1;   // scan: W_rh | aux: W_zh
  short8 Bh0, Bh1;   // scan: W_hh
  short8 Bp0, Bp1;   // waves 4,5: W_proj (vocab tile W8-4)
  float bpj = 0.f;
  {
    const float* Wa = isScan ? Wrh : Wzh;
    Ba0 = load_bfrag(Wa, Hn, jcol, q * 8);
    Ba1 = load_bfrag(Wa, Hn, jcol, 32 + q * 8);
    Bh0 = Ba0; Bh1 = Ba1; Bp0 = Ba0; Bp1 = Ba1;
    if (isScan) {
      Bh0 = load_bfrag(Whh, Hn, jcol, q * 8);
      Bh1 = load_bfrag(Whh, Hn, jcol, 32 + q * 8);
    } else if (W8 < 6) {
      int vt = W8 - 4;
      Bp0 = load_bfrag(Wpj, Vn, vt * 16 + c16, q * 8);
      Bp1 = load_bfrag(Wpj, Vn, vt * 16 + c16, 32 + q * 8);
      bpj = bpj_g[vt * 16 + c16];
    }
  }

  float h[4] = {0.f, 0.f, 0.f, 0.f};
  float nll = 0.f, cnt = 0.f;

  __syncthreads();   // prologue done

  for (int t = 0; t < Tn; ++t) {
    const unsigned int pk = code4_s[t * 4 + q];
    unsigned short tc[4];   // c-gate TBL values, prefetched in A, used in B
    // ===== interval A =====
    {
      const unsigned short* hp = &hist_s[((t + 7) & 7) * 1152];
      short8 a0 = *(const short8*)&hp[c16 * 72 + q * 8];
      short8 a1 = *(const short8*)&hp[c16 * 72 + 32 + q * 8];
      if (isScan) {       // issue c-gate tbl reads early (tbl_s is read-only)
#pragma unroll
        for (int r = 0; r < 4; ++r) {
          int cr = (pk >> (8 * r)) & 255;
          tc[r] = tbl_s[2 * 2112 + cr * 66 + jcol];
        }
      }
      floatx4 acc = __builtin_amdgcn_mfma_f32_16x16x32_bf16(a0, Ba0, zf, 0, 0, 0);
      acc = __builtin_amdgcn_mfma_f32_16x16x32_bf16(a1, Ba1, acc, 0, 0, 0);
      if (isScan) {       // r-gate -> rh_s
#pragma unroll
        for (int r = 0; r < 4; ++r) {
          int cr = (pk >> (8 * r)) & 255;
          float xr = bf2f(tbl_s[0 * 2112 + cr * 66 + jcol]) + ph_a[r] + acc[r];
          rh_s[(q * 4 + r) * 72 + jcol] = f2bf(fast_sigmoid(xr) * h[r]);
        }
      } else {            // z-gate -> z_cm (one b128 write: 4 consecutive m at col jcol)
        floatx4 z4;
#pragma unroll
        for (int r = 0; r < 4; ++r) {
          int cr = (pk >> (8 * r)) & 255;
          float xz = bf2f(tbl_s[1 * 2112 + cr * 66 + jcol]) + ph_a[r] + acc[r];
          z4[r] = fast_sigmoid(xz);
        }
        *(floatx4*)&z_cm[jcol * 20 + q * 4] = z4;
      }
    }
    __syncthreads();  // A

    // ===== interval B =====
    if (isScan) {       // c-gate + h-update -> hist_s[t&7]
      short8 p0 = *(const short8*)&rh_s[c16 * 72 + q * 8];
      short8 p1 = *(const short8*)&rh_s[c16 * 72 + 32 + q * 8];
      floatx4 z4 = *(const floatx4*)&z_cm[jcol * 20 + q * 4];   // one b128 read
      floatx4 acc = __builtin_amdgcn_mfma_f32_16x16x32_bf16(p0, Bh0, zf, 0, 0, 0);
      acc = __builtin_amdgcn_mfma_f32_16x16x32_bf16(p1, Bh1, acc, 0, 0, 0);
      unsigned short* hw = &hist_s[(t & 7) * 1152];
#pragma unroll
      for (int r = 0; r < 4; ++r) {
        float xh = bf2f(tc[r]) + ph_h[r] + acc[r];
        float c = fast_tanh(xh);
        float hn = (1.f - z4[r]) * h[r] + z4[r] * c;
        h[r] = hn;
        hw[(q * 4 + r) * 72 + jcol] = f2bf(hn);
      }
    } else if (W8 < 6) {   // waves 4-5: project h_{t-1} -> logit stage
      if (t > 0) {
        const unsigned short* hp = &hist_s[((t + 7) & 7) * 1152];
        short8 a0 = *(const short8*)&hp[c16 * 72 + q * 8];
        short8 a1 = *(const short8*)&hp[c16 * 72 + 32 + q * 8];
        floatx4 l = __builtin_amdgcn_mfma_f32_16x16x32_bf16(a0, Bp0, zf, 0, 0, 0);
        l = __builtin_amdgcn_mfma_f32_16x16x32_bf16(a1, Bp1, l, 0, 0, 0);
        float* pg = &logit_s[((t - 1) & 7) * 528];
        int vt = W8 - 4;
#pragma unroll
        for (int r = 0; r < 4; ++r)
          pg[(q * 4 + r) * 33 + vt * 16 + c16] = l[r] + bpj;
      }
    }
    __syncthreads();  // B

    // ===== chunk tail: every 8 steps, all 8 waves (one page each, parallel) =====
    if ((t & 7) == 7) {
      int p = t - 8 + W8;           // pages t-8 .. t-1
      if (p >= 0) {
        const float* pg = &logit_s[(p & 7) * 528];
        int v = lane & 31, hf = lane >> 5;
#pragma unroll
        for (int i = 0; i < 8; ++i) {
          int m = i * 2 + hf;
          float lg = pg[m * 33 + v];
          float s = __expf(lg);
#pragma unroll
          for (int off = 16; off >= 1; off >>= 1) s += __shfl_xor(s, off);
          float lse = __logf(s);     // |logits| <= ~8, safe without max-sub
          outp[(((long)(b0 + m)) * Tn + p) * Vn + v] = lg;
          unsigned int pk1 = code4_s[(p + 1) * 4 + (m >> 2)];
          int targ = (pk1 >> (8 * (m & 3))) & 255;
          if (targ != 0 && v == targ) { nll += lse - lg; cnt += 1.f; }
        }
      }
    }
  }

  // ===== epilogue: project + finalize t = 63 =====
  __syncthreads();
  if (W8 >= 4 && W8 < 6) {
    const unsigned short* hp = &hist_s[7 * 1152];   // h_63
    short8 a0 = *(const short8*)&hp[c16 * 72 + q * 8];
    short8 a1 = *(const short8*)&hp[c16 * 72 + 32 + q * 8];
    floatx4 l = __builtin_amdgcn_mfma_f32_16x16x32_bf16(a0, Bp0, zf, 0, 0, 0);
    l = __builtin_amdgcn_mfma_f32_16x16x32_bf16(a1, Bp1, l, 0, 0, 0);
    int vt = W8 - 4;
#pragma unroll
    for (int r = 0; r < 4; ++r)
      logit_s[7 * 528 + (q * 4 + r) * 33 + vt * 16 + c16] = l[r] + bpj;
  }
  __syncthreads();
  if (W8 == 0) {
    const float* pg = &logit_s[7 * 528];
    int v = lane & 31, hf = lane >> 5;
#pragma unroll
    for (int i = 0; i < 8; ++i) {
      int m = i * 2 + hf;
      float lg = pg[m * 33 + v];
      float s = __expf(lg);
#pragma unroll
      for (int off = 16; off >= 1; off >>= 1) s += __shfl_xor(s, off);
      float lse = __logf(s);
      outp[(((long)(b0 + m)) * Tn + 63) * Vn + v] = lg;
      unsigned int pk1 = code4_s[64 * 4 + (m >> 2)];
      int targ = (pk1 >> (8 * (m & 3))) & 255;
      if (targ != 0 && v == targ) { nll += lse - lg; cnt += 1.f; }
    }
  }

  // ===== reduction -> per-block ws slot =====
#pragma unroll
  for (int off = 32; off >= 1; off >>= 1) {
    nll += __shfl_xor(nll, off);
    cnt += __shfl_xor(cnt, off);
  }
  if (lane == 0) { red_s[W8] = nll; red_s[8 + W8] = cnt; }
  __syncthreads();
  if (tid == 0) {
    float n = 0.f, c = 0.f;
#pragma unroll
    for (int i = 0; i < 8; ++i) { n += red_s[i]; c += red_s[8 + i]; }
    ws[2 * blockIdx.x] = n;
    ws[2 * blockIdx.x + 1] = c;
  }
}

__global__ void loss_kernel(const float* __restrict__ ws, float* __restrict__ outp) {
  int lane = threadIdx.x;  // 64 threads
  float n = 0.f, c = 0.f;
  for (int i = lane; i < Bsz / 16; i += 64) { n += ws[2 * i]; c += ws[2 * i + 1]; }
#pragma unroll
  for (int off = 32; off >= 1; off >>= 1) {
    n += __shfl_xor(n, off);
    c += __shfl_xor(c, off);
  }
  if (lane == 0) outp[(size_t)Bsz * Tn * Vn] = n / fmaxf(c, 1.f);
}

extern "C" void kernel_launch(void* const* d_in, const int* in_sizes, int n_in,
                              void* d_out, int out_size, void* d_ws, size_t ws_size,
                              hipStream_t stream) {
  const float* phon = (const float*)d_in[0];
  const int*   cs   = (const int*)d_in[1];
  const float* emb  = (const float*)d_in[2];
  const float* Wrx  = (const float*)d_in[3];
  const float* brx  = (const float*)d_in[4];
  const float* Wrh  = (const float*)d_in[5];
  const float* brh  = (const float*)d_in[6];
  const float* Wzx  = (const float*)d_in[7];
  const float* bzx  = (const float*)d_in[8];
  const float* Wzh  = (const float*)d_in[9];
  const float* bzh  = (const float*)d_in[10];
  const float* Whx  = (const float*)d_in[11];
  const float* bhx  = (const float*)d_in[12];
  const float* Whh  = (const float*)d_in[13];
  const float* bhh  = (const float*)d_in[14];
  const float* Wpj  = (const float*)d_in[15];
  const float* bpj  = (const float*)d_in[16];
  float* ws = (float*)d_ws;

  hipLaunchKernelGGL(gru_kernel, dim3(Bsz / 16), dim3(512), 0, stream,
                     phon, cs, emb, Wrx, brx, Wrh, brh, Wzx, bzx, Wzh, bzh,
                     Whx, bhx, Whh, bhh, Wpj, bpj, ws, (float*)d_out);
  hipLaunchKernelGGL(loss_kernel, dim3(1), dim3(64), 0, stream, ws, (float*)d_out);
}

// Round 13
// 170.751 us; speedup vs baseline: 1.1355x; 1.0285x over previous
//
#include <hip/hip_runtime.h>
#include <stdint.h>

// Problem constants
#define Bsz 4096
#define Tn  64      // scan length (char_seq[:, :-1])
#define T1n 65
#define Hn  64
#define Pn  50
#define Vn  32

typedef __attribute__((ext_vector_type(8))) short short8;
typedef __attribute__((ext_vector_type(4))) float floatx4;

__device__ __forceinline__ float bf2f(unsigned short u) {
  union { unsigned int i; float f; } x; x.i = ((unsigned int)u) << 16; return x.f;
}
__device__ __forceinline__ unsigned short f2bf(float f) {
  union { float f; unsigned int i; } x; x.f = f;
  return (unsigned short)((x.i + 0x7FFFu + ((x.i >> 16) & 1u)) >> 16);
}
__device__ __forceinline__ float fast_sigmoid(float x) {
  return __builtin_amdgcn_rcpf(1.f + __expf(-x));
}
__device__ __forceinline__ float fast_tanh(float x) {
  return 1.f - 2.f * __builtin_amdgcn_rcpf(1.f + __expf(2.f * x));
}

// B-operand fragment for mfma_f32_16x16x32_bf16 from row-major (K x ncols) fp32 weights.
__device__ __forceinline__ short8 load_bfrag(const float* __restrict__ W, int ncols, int col, int kbase) {
  short8 f;
#pragma unroll
  for (int j = 0; j < 8; ++j) f[j] = (short)f2bf(W[(long)(kbase + j) * ncols + col]);
  return f;
}

// Fused GRU, R13: scan waves own r AND z (two independent MFMA chains in
// interval A -> ILP, no z exchange); proj waves run in interval A on h_{t-1};
// waves 6-7 idle per-step (tail only). 256 blocks x 512 threads (8 waves),
// block owns 16 batch rows; scan wave w covers cols [16w,16w+16).
// Logit pages mod 9 so tail reads and proj writes never alias without >=2
// intervening barriers.
__launch_bounds__(512)
__global__ void gru_kernel(const float* __restrict__ phon,
                           const int* __restrict__ cs,
                           const float* __restrict__ emb,
                           const float* __restrict__ Wrx, const float* __restrict__ brx,
                           const float* __restrict__ Wrh, const float* __restrict__ brh,
                           const float* __restrict__ Wzx, const float* __restrict__ bzx,
                           const float* __restrict__ Wzh, const float* __restrict__ bzh,
                           const float* __restrict__ Whx, const float* __restrict__ bhx,
                           const float* __restrict__ Whh, const float* __restrict__ bhh,
                           const float* __restrict__ Wpj, const float* __restrict__ bpj_g,
                           float* __restrict__ ws,
                           float* __restrict__ outp) {
  __shared__ unsigned short tbl_s[3 * 32 * 66];             // bf16 [g][v][66]
  __shared__ __align__(16) unsigned short hist_s[8 * 1152]; // bf16 h[t&7][m][72]
  __shared__ __align__(16) unsigned short rh_s[1152];       // bf16 r*h [m][72]
  __shared__ float logit_s[9 * 16 * 33];                    // f32 [page%9][m][33]
  __shared__ unsigned int code4_s[(T1n + 1) * 4];           // packed codes [t][q]
  __shared__ int det_s[1];
  __shared__ float red_s[16];

  const int tid = threadIdx.x;
  const int b0 = blockIdx.x * 16;
  const int W8 = tid >> 6, lane = tid & 63, q = lane >> 4, c16 = lane & 15;
  const bool isScan = (W8 < 4);
  const int w = isScan ? W8 : (W8 - 4);
  const int jcol = w * 16 + c16;
  const floatx4 zf = {0.f, 0.f, 0.f, 0.f};

  // --- int32-vs-int64 detection for char_seq ---
  if (tid == 0) det_s[0] = 0;
  __syncthreads();
  if (tid < 128 && cs[2 * tid + 1] != 0) atomicOr(&det_s[0], 1);
  __syncthreads();
  const bool is64 = (det_s[0] == 0);

  // --- staging ---
  for (int i = tid; i < 1152; i += 512) hist_s[7 * 1152 + i] = 0;   // h0 slot
  for (int i = tid; i < T1n * 4; i += 512) {
    int t = i >> 2, qq = i & 3;
    unsigned int pk = 0;
#pragma unroll
    for (int r = 0; r < 4; ++r) {
      long idx = (long)(b0 + qq * 4 + r) * T1n + t;
      int c = is64 ? cs[2 * idx] : cs[idx];
      pk |= ((unsigned int)(c & 255)) << (8 * r);
    }
    code4_s[i] = pk;
  }

  // --- TBL: tbl_s[g][v][j] = bf16( emb[v] @ W_gx[:64] + b_gx[j] + b_gh[j] ) ---
  for (int g = 0; g < 3; ++g) {
    const float* Wg = (g == 0) ? Wrx : (g == 1) ? Wzx : Whx;
    const float* bx = (g == 0) ? brx : (g == 1) ? bzx : bhx;
    const float* bh = (g == 0) ? brh : (g == 1) ? bzh : bhh;
    float acc[4] = {0.f, 0.f, 0.f, 0.f};
    float bias = bx[lane] + bh[lane];
    for (int d = 0; d < Hn; ++d) {
      float wv = Wg[(long)d * Hn + lane];
#pragma unroll
      for (int k = 0; k < 4; ++k)
        acc[k] += emb[(long)(W8 + 8 * k) * Hn + d] * wv;
    }
#pragma unroll
    for (int k = 0; k < 4; ++k)
      tbl_s[g * 2112 + (W8 + 8 * k) * 66 + lane] = f2bf(acc[k] + bias);
  }

  // --- PH per-lane (scan waves only): r, z, h gates ---
  float ph_r[4] = {0.f, 0.f, 0.f, 0.f};
  float ph_z[4] = {0.f, 0.f, 0.f, 0.f};
  float ph_h[4] = {0.f, 0.f, 0.f, 0.f};
  if (isScan) {
    for (int p = 0; p < Pn; ++p) {
      float wr = Wrx[(long)(Hn + p) * Hn + jcol];
      float wz = Wzx[(long)(Hn + p) * Hn + jcol];
      float wh = Whx[(long)(Hn + p) * Hn + jcol];
#pragma unroll
      for (int r = 0; r < 4; ++r) {
        float xv = phon[(long)(b0 + q * 4 + r) * Pn + p];
        ph_r[r] += xv * wr; ph_z[r] += xv * wz; ph_h[r] += xv * wh;
      }
    }
  }

  // --- B-fragments (register-resident, t-invariant) ---
  short8 Br0, Br1, Bz0, Bz1, Bh0, Bh1;   // scan: W_rh, W_zh, W_hh
  short8 Bp0, Bp1;                        // waves 4,5: W_proj (vocab tile W8-4)
  float bpj = 0.f;
  if (isScan) {
    Br0 = load_bfrag(Wrh, Hn, jcol, q * 8);
    Br1 = load_bfrag(Wrh, Hn, jcol, 32 + q * 8);
    Bz0 = load_bfrag(Wzh, Hn, jcol, q * 8);
    Bz1 = load_bfrag(Wzh, Hn, jcol, 32 + q * 8);
    Bh0 = load_bfrag(Whh, Hn, jcol, q * 8);
    Bh1 = load_bfrag(Whh, Hn, jcol, 32 + q * 8);
    Bp0 = Br0; Bp1 = Br1;
  } else if (W8 < 6) {
    int vt = W8 - 4;
    Bp0 = load_bfrag(Wpj, Vn, vt * 16 + c16, q * 8);
    Bp1 = load_bfrag(Wpj, Vn, vt * 16 + c16, 32 + q * 8);
    bpj = bpj_g[vt * 16 + c16];
    Br0 = Bp0; Br1 = Bp1; Bz0 = Bp0; Bz1 = Bp1; Bh0 = Bp0; Bh1 = Bp1;
  } else {
    short8 zs = {0,0,0,0,0,0,0,0};
    Br0 = zs; Br1 = zs; Bz0 = zs; Bz1 = zs; Bh0 = zs; Bh1 = zs; Bp0 = zs; Bp1 = zs;
  }

  float h[4] = {0.f, 0.f, 0.f, 0.f};
  float z4[4] = {0.f, 0.f, 0.f, 0.f};
  float nll = 0.f, cnt = 0.f;
  int pp = 0;   // proj page counter = (t-1) % 9 when t >= 1 (aux-uniform)

  __syncthreads();   // prologue done

  for (int t = 0; t < Tn; ++t) {
    const unsigned int pk = code4_s[t * 4 + q];
    unsigned short tc[4];   // c-gate TBL values, prefetched in A, used in B
    // ===== interval A =====
    if (isScan) {
      const unsigned short* hp = &hist_s[((t + 7) & 7) * 1152];
      short8 a0 = *(const short8*)&hp[c16 * 72 + q * 8];
      short8 a1 = *(const short8*)&hp[c16 * 72 + 32 + q * 8];
      floatx4 accr = __builtin_amdgcn_mfma_f32_16x16x32_bf16(a0, Br0, zf, 0, 0, 0);
      floatx4 accz = __builtin_amdgcn_mfma_f32_16x16x32_bf16(a0, Bz0, zf, 0, 0, 0);
      accr = __builtin_amdgcn_mfma_f32_16x16x32_bf16(a1, Br1, accr, 0, 0, 0);
      accz = __builtin_amdgcn_mfma_f32_16x16x32_bf16(a1, Bz1, accz, 0, 0, 0);
#pragma unroll
      for (int r = 0; r < 4; ++r) {
        int cr = (pk >> (8 * r)) & 255;
        tc[r] = tbl_s[2 * 2112 + cr * 66 + jcol];
        float xr = bf2f(tbl_s[0 * 2112 + cr * 66 + jcol]) + ph_r[r] + accr[r];
        float xz = bf2f(tbl_s[1 * 2112 + cr * 66 + jcol]) + ph_z[r] + accz[r];
        z4[r] = fast_sigmoid(xz);
        rh_s[(q * 4 + r) * 72 + jcol] = f2bf(fast_sigmoid(xr) * h[r]);
      }
    } else if (W8 < 6 && t > 0) {   // proj h_{t-1} -> logit page (t-1)%9
      const unsigned short* hp = &hist_s[((t + 7) & 7) * 1152];
      short8 a0 = *(const short8*)&hp[c16 * 72 + q * 8];
      short8 a1 = *(const short8*)&hp[c16 * 72 + 32 + q * 8];
      floatx4 l = __builtin_amdgcn_mfma_f32_16x16x32_bf16(a0, Bp0, zf, 0, 0, 0);
      l = __builtin_amdgcn_mfma_f32_16x16x32_bf16(a1, Bp1, l, 0, 0, 0);
      float* pg = &logit_s[pp * 528];
      int vt = W8 - 4;
#pragma unroll
      for (int r = 0; r < 4; ++r)
        pg[(q * 4 + r) * 33 + vt * 16 + c16] = l[r] + bpj;
      pp = (pp == 8) ? 0 : pp + 1;
    }
    __syncthreads();  // A

    // ===== interval B =====
    if (isScan) {       // c-gate + h-update -> hist_s[t&7]
      short8 p0 = *(const short8*)&rh_s[c16 * 72 + q * 8];
      short8 p1 = *(const short8*)&rh_s[c16 * 72 + 32 + q * 8];
      floatx4 acc = __builtin_amdgcn_mfma_f32_16x16x32_bf16(p0, Bh0, zf, 0, 0, 0);
      acc = __builtin_amdgcn_mfma_f32_16x16x32_bf16(p1, Bh1, acc, 0, 0, 0);
      unsigned short* hw = &hist_s[(t & 7) * 1152];
#pragma unroll
      for (int r = 0; r < 4; ++r) {
        float xh = bf2f(tc[r]) + ph_h[r] + acc[r];
        float c = fast_tanh(xh);
        float hn = fmaf(z4[r], c - h[r], h[r]);
        h[r] = hn;
        hw[(q * 4 + r) * 72 + jcol] = f2bf(hn);
      }
    }
    __syncthreads();  // B

    // ===== chunk tail: every 8 steps, all 8 waves (one page each, parallel) =====
    if ((t & 7) == 7) {
      int p = t - 8 + W8;           // pages t-8 .. t-1
      if (p >= 0) {
        const float* pg = &logit_s[(p % 9) * 528];
        int v = lane & 31, hf = lane >> 5;
#pragma unroll
        for (int i = 0; i < 8; ++i) {
          int m = i * 2 + hf;
          float lg = pg[m * 33 + v];
          float s = __expf(lg);
#pragma unroll
          for (int off = 16; off >= 1; off >>= 1) s += __shfl_xor(s, off);
          float lse = __logf(s);     // |logits| <= ~8, safe without max-sub
          outp[(((long)(b0 + m)) * Tn + p) * Vn + v] = lg;
          unsigned int pk1 = code4_s[(p + 1) * 4 + (m >> 2)];
          int targ = (pk1 >> (8 * (m & 3))) & 255;
          if (targ != 0 && v == targ) { nll += lse - lg; cnt += 1.f; }
        }
      }
    }
  }

  // ===== epilogue: project + finalize page 63 (slot 63%9 == 0) =====
  if (W8 >= 4 && W8 < 6) {
    const unsigned short* hp = &hist_s[7 * 1152];   // h_63
    short8 a0 = *(const short8*)&hp[c16 * 72 + q * 8];
    short8 a1 = *(const short8*)&hp[c16 * 72 + 32 + q * 8];
    floatx4 l = __builtin_amdgcn_mfma_f32_16x16x32_bf16(a0, Bp0, zf, 0, 0, 0);
    l = __builtin_amdgcn_mfma_f32_16x16x32_bf16(a1, Bp1, l, 0, 0, 0);
    int vt = W8 - 4;
#pragma unroll
    for (int r = 0; r < 4; ++r)
      logit_s[0 * 528 + (q * 4 + r) * 33 + vt * 16 + c16] = l[r] + bpj;
  }
  __syncthreads();
  if (W8 == 0) {
    const float* pg = &logit_s[0 * 528];
    int v = lane & 31, hf = lane >> 5;
#pragma unroll
    for (int i = 0; i < 8; ++i) {
      int m = i * 2 + hf;
      float lg = pg[m * 33 + v];
      float s = __expf(lg);
#pragma unroll
      for (int off = 16; off >= 1; off >>= 1) s += __shfl_xor(s, off);
      float lse = __logf(s);
      outp[(((long)(b0 + m)) * Tn + 63) * Vn + v] = lg;
      unsigned int pk1 = code4_s[64 * 4 + (m >> 2)];
      int targ = (pk1 >> (8 * (m & 3))) & 255;
      if (targ != 0 && v == targ) { nll += lse - lg; cnt += 1.f; }
    }
  }

  // ===== reduction -> per-block ws slot =====
#pragma unroll
  for (int off = 32; off >= 1; off >>= 1) {
    nll += __shfl_xor(nll, off);
    cnt += __shfl_xor(cnt, off);
  }
  if (lane == 0) { red_s[W8] = nll; red_s[8 + W8] = cnt; }
  __syncthreads();
  if (tid == 0) {
    float n = 0.f, c = 0.f;
#pragma unroll
    for (int i = 0; i < 8; ++i) { n += red_s[i]; c += red_s[8 + i]; }
    ws[2 * blockIdx.x] = n;
    ws[2 * blockIdx.x + 1] = c;
  }
}

__global__ void loss_kernel(const float* __restrict__ ws, float* __restrict__ outp) {
  int lane = threadIdx.x;  // 64 threads
  float n = 0.f, c = 0.f;
  for (int i = lane; i < Bsz / 16; i += 64) { n += ws[2 * i]; c += ws[2 * i + 1]; }
#pragma unroll
  for (int off = 32; off >= 1; off >>= 1) {
    n += __shfl_xor(n, off);
    c += __shfl_xor(c, off);
  }
  if (lane == 0) outp[(size_t)Bsz * Tn * Vn] = n / fmaxf(c, 1.f);
}

extern "C" void kernel_launch(void* const* d_in, const int* in_sizes, int n_in,
                              void* d_out, int out_size, void* d_ws, size_t ws_size,
                              hipStream_t stream) {
  const float* phon = (const float*)d_in[0];
  const int*   cs   = (const int*)d_in[1];
  const float* emb  = (const float*)d_in[2];
  const float* Wrx  = (const float*)d_in[3];
  const float* brx  = (const float*)d_in[4];
  const float* Wrh  = (const float*)d_in[5];
  const float* brh  = (const float*)d_in[6];
  const float* Wzx  = (const float*)d_in[7];
  const float* bzx  = (const float*)d_in[8];
  const float* Wzh  = (const float*)d_in[9];
  const float* bzh  = (const float*)d_in[10];
  const float* Whx  = (const float*)d_in[11];
  const float* bhx  = (const float*)d_in[12];
  const float* Whh  = (const float*)d_in[13];
  const float* bhh  = (const float*)d_in[14];
  const float* Wpj  = (const float*)d_in[15];
  const float* bpj  = (const float*)d_in[16];
  float* ws = (float*)d_ws;

  hipLaunchKernelGGL(gru_kernel, dim3(Bsz / 16), dim3(512), 0, stream,
                     phon, cs, emb, Wrx, brx, Wrh, brh, Wzx, bzx, Wzh, bzh,
                     Whx, bhx, Whh, bhh, Wpj, bpj, ws, (float*)d_out);
  hipLaunchKernelGGL(loss_kernel, dim3(1), dim3(64), 0, stream, ws, (float*)d_out);
}